// Round 1
// baseline (550.147 us; speedup 1.0000x reference)
//
#include <hip/hip_runtime.h>

// Problem constants: B=4, S=T=16, DIM=512, H=W=32, HEADS=8, dh=64
// q,k,v: [4,16,512,32,32] fp32 (33,554,432 elems each); Wq/Wk/Wv: [512,512] fp32.
// out: [4,16,512,32,32] fp32.
//
// Pipeline (v4):
//  k_means : persistent waves (2048 blocks), 8 channels/wave, 2 in flight
//  k_trans : 4 bt-tiles per block; vT stored FP16 (range-safe: |v| < 6)
//  k_attn  : Wv->fp16; attnT[b,h][t][s] = softmax over t of (qh.kh)  (fp32)
//  k_gemm  : VP[b,t][d][p] = sum_c Wv[d,c]*vT[t,p,c]  (fp16 MFMA, fp32 acc)
//            epilogue: fp16 VP into workspace (if it fits) else fp32 -> d_out
//  k_mix   : out[b,s,d,p] = sum_t attnT[t][s]*VP[b,t,d,p]
//            fp16-VP variant (ws) or in-place fp32 fallback (d_out)

typedef __attribute__((ext_vector_type(8))) _Float16 f16x8;
typedef __attribute__((ext_vector_type(4))) _Float16 f16x4;
typedef __attribute__((ext_vector_type(4))) float f32x4;

__device__ __forceinline__ unsigned short f2h(float f) {
  union { _Float16 h; unsigned short u; } x;
  x.h = (_Float16)f;   // v_cvt_f16_f32, RTN
  return x.u;
}

// ---------------------------------------------------------------- k_means
// grid 2048 x 256 (8192 persistent waves). Each wave sums 8 channels
// (32 KB contiguous), 2 channels in flight per iteration (8 float4 loads).
__global__ __launch_bounds__(256) void k_means(const float* __restrict__ q,
                                               const float* __restrict__ k,
                                               float* __restrict__ qm,
                                               float* __restrict__ km) {
  int gw = blockIdx.x * 4 + (threadIdx.x >> 6);   // 0..8191
  int lane = threadIdx.x & 63;
  int ch0 = gw * 8;                               // 65536 channels total (q then k)
  const float* src = q; float* dst = qm; int base = ch0;
  if (ch0 >= 32768) { src = k; dst = km; base = ch0 - 32768; }
  const float4* p = (const float4*)src;
#pragma unroll
  for (int j = 0; j < 8; j += 2) {
    const float4* p0 = p + (size_t)(base + j) * 256;   // 1 channel = 256 float4
    const float4* p1 = p0 + 256;
    float4 a0 = p0[lane], a1 = p0[64 + lane], a2 = p0[128 + lane], a3 = p0[192 + lane];
    float4 b0 = p1[lane], b1 = p1[64 + lane], b2 = p1[128 + lane], b3 = p1[192 + lane];
    float s0 = (a0.x + a0.y + a0.z + a0.w) + (a1.x + a1.y + a1.z + a1.w) +
               (a2.x + a2.y + a2.z + a2.w) + (a3.x + a3.y + a3.z + a3.w);
    float s1 = (b0.x + b0.y + b0.z + b0.w) + (b1.x + b1.y + b1.z + b1.w) +
               (b2.x + b2.y + b2.z + b2.w) + (b3.x + b3.y + b3.z + b3.w);
#pragma unroll
    for (int off = 32; off > 0; off >>= 1) {
      s0 += __shfl_down(s0, off);
      s1 += __shfl_down(s1, off);
    }
    if (lane == 0) {
      dst[base + j]     = s0 * (1.0f / 1024.0f);
      dst[base + j + 1] = s1 * (1.0f / 1024.0f);
    }
  }
}

// ---------------------------------------------------------------- k_trans
// grid (16 m-tiles, 8 c-tiles, 16 z) x 256; each block loops 4 bt tiles.
// 64x64 tile transpose + fp32->fp16. Row permutation m(x)=(x%32)*32+x/32
// folded in so the GEMM's output column index is the final output pixel.
__global__ __launch_bounds__(256) void k_trans(const float* __restrict__ v,
                                               unsigned short* __restrict__ vT) {
  int tid = threadIdx.x;
  int m0 = blockIdx.x * 64, c0 = blockIdx.y * 64;
  __shared__ float ls[64 * 65];
  for (int it = 0; it < 4; ++it) {
    int bt = blockIdx.z * 4 + it;
    const float* src = v + (size_t)bt * 524288;
    if (it) __syncthreads();
#pragma unroll
    for (int p = 0; p < 4; ++p) {
      int r = p * 16 + (tid >> 4);
      int mm4 = (tid & 15) * 4;
      float4 f = *(const float4*)&src[(size_t)(c0 + r) * 1024 + m0 + mm4];
      ls[r * 65 + mm4 + 0] = f.x;
      ls[r * 65 + mm4 + 1] = f.y;
      ls[r * 65 + mm4 + 2] = f.z;
      ls[r * 65 + mm4 + 3] = f.w;
    }
    __syncthreads();
    unsigned short* dst = vT + (size_t)bt * 524288;
#pragma unroll
    for (int p = 0; p < 2; ++p) {
      int mm = p * 32 + (tid >> 3);
      int cr8 = (tid & 7) * 8;
      unsigned int w[4];
#pragma unroll
      for (int e = 0; e < 4; ++e) {
        unsigned short lo = f2h(ls[(cr8 + 2 * e + 0) * 65 + mm]);
        unsigned short hi = f2h(ls[(cr8 + 2 * e + 1) * 65 + mm]);
        w[e] = (unsigned int)lo | ((unsigned int)hi << 16);
      }
      uint4 pk = {w[0], w[1], w[2], w[3]};
      int x = m0 + mm;                           // memory pixel index
      int rr = ((x & 31) << 5) | (x >> 5);       // permuted destination row
      *(uint4*)&dst[(size_t)rr * 512 + c0 + cr8] = pk;
    }
  }
}

// ---------------------------------------------------------------- k_attn
// grid 32 (b*8+h) x 256. Also converts Wv -> fp16. attn stored [t][s], fp32.
__global__ __launch_bounds__(256) void k_attn(const float* __restrict__ qm,
                                              const float* __restrict__ km,
                                              const float* __restrict__ Wq,
                                              const float* __restrict__ Wk,
                                              const float* __restrict__ Wv,
                                              unsigned short* __restrict__ Wv_h,
                                              float* __restrict__ attnT) {
  int tid = threadIdx.x;
  int b = blockIdx.x >> 3, h = blockIdx.x & 7;
  // Wv -> fp16 (65536 float4 across 8192 threads)
  {
    const float4* s4 = (const float4*)Wv;
#pragma unroll
    for (int i = 0; i < 8; ++i) {
      int idx = blockIdx.x * 256 + tid + i * 8192;
      float4 f = s4[idx];
      ushort4 u;
      u.x = f2h(f.x); u.y = f2h(f.y); u.z = f2h(f.z); u.w = f2h(f.w);
      *(ushort4*)&Wv_h[(size_t)idx * 4] = u;
    }
  }
  __shared__ float WS[64 * 65];
  __shared__ float xS[16 * 64];
  __shared__ float qhS[16 * 65];
  __shared__ float khS[16 * 65];
  __shared__ float lg[16 * 17];
  int j = tid & 63, so = tid >> 6;
  float acc[4];

  // ---- qh = (qm @ Wq.T) * scale ----
  acc[0] = acc[1] = acc[2] = acc[3] = 0.f;
  for (int c0 = 0; c0 < 512; c0 += 64) {
    __syncthreads();
#pragma unroll
    for (int p = 0; p < 4; ++p) {
      int r = p * 16 + (tid >> 4);
      int c4 = (tid & 15) * 4;
      float4 f = *(const float4*)&Wq[(size_t)(h * 64 + r) * 512 + c0 + c4];
      WS[r * 65 + c4 + 0] = f.x; WS[r * 65 + c4 + 1] = f.y;
      WS[r * 65 + c4 + 2] = f.z; WS[r * 65 + c4 + 3] = f.w;
    }
    {
      int s = tid >> 4;
      int c4 = (tid & 15) * 4;
      float4 f = *(const float4*)&qm[(size_t)(b * 16 + s) * 512 + c0 + c4];
      xS[s * 64 + c4 + 0] = f.x; xS[s * 64 + c4 + 1] = f.y;
      xS[s * 64 + c4 + 2] = f.z; xS[s * 64 + c4 + 3] = f.w;
    }
    __syncthreads();
    for (int cc = 0; cc < 64; ++cc) {
      float wv = WS[j * 65 + cc];
#pragma unroll
      for (int o = 0; o < 4; ++o) acc[o] += xS[(o * 4 + so) * 64 + cc] * wv;
    }
  }
#pragma unroll
  for (int o = 0; o < 4; ++o) qhS[(o * 4 + so) * 65 + j] = acc[o] * 0.125f;

  // ---- kh = km @ Wk.T ----
  acc[0] = acc[1] = acc[2] = acc[3] = 0.f;
  for (int c0 = 0; c0 < 512; c0 += 64) {
    __syncthreads();
#pragma unroll
    for (int p = 0; p < 4; ++p) {
      int r = p * 16 + (tid >> 4);
      int c4 = (tid & 15) * 4;
      float4 f = *(const float4*)&Wk[(size_t)(h * 64 + r) * 512 + c0 + c4];
      WS[r * 65 + c4 + 0] = f.x; WS[r * 65 + c4 + 1] = f.y;
      WS[r * 65 + c4 + 2] = f.z; WS[r * 65 + c4 + 3] = f.w;
    }
    {
      int s = tid >> 4;
      int c4 = (tid & 15) * 4;
      float4 f = *(const float4*)&km[(size_t)(b * 16 + s) * 512 + c0 + c4];
      xS[s * 64 + c4 + 0] = f.x; xS[s * 64 + c4 + 1] = f.y;
      xS[s * 64 + c4 + 2] = f.z; xS[s * 64 + c4 + 3] = f.w;
    }
    __syncthreads();
    for (int cc = 0; cc < 64; ++cc) {
      float wv = WS[j * 65 + cc];
#pragma unroll
      for (int o = 0; o < 4; ++o) acc[o] += xS[(o * 4 + so) * 64 + cc] * wv;
    }
  }
#pragma unroll
  for (int o = 0; o < 4; ++o) khS[(o * 4 + so) * 65 + j] = acc[o];
  __syncthreads();

  // logits + softmax (stored transposed: [t][s])
  {
    int s = tid >> 4, t = tid & 15;
    float a = 0.f;
    for (int jj = 0; jj < 64; ++jj) a += qhS[s * 65 + jj] * khS[t * 65 + jj];
    lg[s * 17 + t] = a;
  }
  __syncthreads();
  if (tid < 16) {
    int s = tid;
    float mx = -1e30f;
#pragma unroll
    for (int t = 0; t < 16; ++t) mx = fmaxf(mx, lg[s * 17 + t]);
    float e[16], sum = 0.f;
#pragma unroll
    for (int t = 0; t < 16; ++t) { e[t] = __expf(lg[s * 17 + t] - mx); sum += e[t]; }
    float inv = 1.0f / sum;
#pragma unroll
    for (int t = 0; t < 16; ++t)
      attnT[(blockIdx.x) * 256 + t * 16 + s] = e[t] * inv;
  }
}

// ---------------------------------------------------------------- k_gemm
// grid (8 p-tiles, 4 d-tiles, 64 bt) x 256. m97 structure: 128x128 tile, BK=32,
// 4 waves (2x2 of 64x64), 16x16x32 f16 MFMA, global_load_lds 16B staging.
// VP[d][p] = sum_c Wv[d][c] * vT[p][c].  Epilogue: fp16 (ws) or fp32 (d_out).
__global__ __launch_bounds__(256) void k_gemm(const unsigned short* __restrict__ Wv_h,
                                              const unsigned short* __restrict__ vT,
                                              void* __restrict__ VP, int f16out) {
  int tid = threadIdx.x;
  int bx = blockIdx.x, by = blockIdx.y, bz = blockIdx.z;
  __shared__ __align__(16) unsigned short As[128 * 32];
  __shared__ __align__(16) unsigned short Bs[128 * 32];
  const unsigned short* Ag = Wv_h + (size_t)(by * 128) * 512;
  const unsigned short* Bg = vT + (size_t)bz * 524288 + (size_t)(bx * 128) * 512;
  int r = tid >> 2;           // 0..63 (staging row)
  int c8 = (tid & 3) * 8;     // k offset within BK=32
  int lane = tid & 63, wave = tid >> 6;
  int wd = wave >> 1, wm = wave & 1;
  int l15 = lane & 15, quad = lane >> 4;

  f32x4 acc[4][4];
#pragma unroll
  for (int i = 0; i < 4; ++i)
#pragma unroll
    for (int j = 0; j < 4; ++j) acc[i][j] = (f32x4){0.f, 0.f, 0.f, 0.f};

  for (int kk = 0; kk < 16; ++kk) {
    int c0 = kk * 32;
    if (kk) __syncthreads();
    __builtin_amdgcn_global_load_lds(
        (const __attribute__((address_space(1))) void*)(Ag + (size_t)r * 512 + c0 + c8),
        (__attribute__((address_space(3))) void*)&As[tid * 8], 16, 0, 0);
    __builtin_amdgcn_global_load_lds(
        (const __attribute__((address_space(1))) void*)(Ag + (size_t)(r + 64) * 512 + c0 + c8),
        (__attribute__((address_space(3))) void*)&As[2048 + tid * 8], 16, 0, 0);
    __builtin_amdgcn_global_load_lds(
        (const __attribute__((address_space(1))) void*)(Bg + (size_t)r * 512 + c0 + c8),
        (__attribute__((address_space(3))) void*)&Bs[tid * 8], 16, 0, 0);
    __builtin_amdgcn_global_load_lds(
        (const __attribute__((address_space(1))) void*)(Bg + (size_t)(r + 64) * 512 + c0 + c8),
        (__attribute__((address_space(3))) void*)&Bs[2048 + tid * 8], 16, 0, 0);
    __syncthreads();  // compiler drains vmcnt before s_barrier (m97-verified)

    f16x8 af[4], bfr[4];
#pragma unroll
    for (int i = 0; i < 4; ++i)
      af[i] = *(const f16x8*)&As[(wd * 64 + i * 16 + l15) * 32 + quad * 8];
#pragma unroll
    for (int j = 0; j < 4; ++j)
      bfr[j] = *(const f16x8*)&Bs[(wm * 64 + j * 16 + l15) * 32 + quad * 8];
#pragma unroll
    for (int i = 0; i < 4; ++i)
#pragma unroll
      for (int j = 0; j < 4; ++j)
        acc[i][j] = __builtin_amdgcn_mfma_f32_16x16x32_f16(af[i], bfr[j], acc[i][j], 0, 0, 0);
  }

  if (f16out) {
    _Float16* outp = (_Float16*)VP + (size_t)bz * 524288;
#pragma unroll
    for (int i = 0; i < 4; ++i)
#pragma unroll
      for (int j = 0; j < 4; ++j) {
        int m = bx * 128 + wm * 64 + j * 16 + l15;
#pragma unroll
        for (int rr = 0; rr < 4; ++rr) {
          int d = by * 128 + wd * 64 + i * 16 + quad * 4 + rr;
          outp[(size_t)d * 1024 + m] = (_Float16)acc[i][j][rr];
        }
      }
  } else {
    float* outp = (float*)VP + (size_t)bz * 524288;
#pragma unroll
    for (int i = 0; i < 4; ++i)
#pragma unroll
      for (int j = 0; j < 4; ++j) {
        int m = bx * 128 + wm * 64 + j * 16 + l15;
#pragma unroll
        for (int rr = 0; rr < 4; ++rr) {
          int d = by * 128 + wd * 64 + i * 16 + quad * 4 + rr;
          outp[(size_t)d * 1024 + m] = acc[i][j][rr];
        }
      }
  }
}

// ---------------------------------------------------------------- k_mix_f16
// grid 2048 (b*512+d) x 256. Reads fp16 VP from workspace, writes fp32 out.
// Thread owns 4 contiguous pixels of column d; block-uniform attnT (s_load).
__global__ __launch_bounds__(256) void k_mix_f16(const _Float16* __restrict__ VP,
                                                 float* __restrict__ out,
                                                 const float* __restrict__ attnT) {
  int blk = blockIdx.x;
  int b = blk >> 9, d = blk & 511, h = d >> 6;
  int tid = threadIdx.x;
  const float* at = attnT + (b * 8 + h) * 256;  // [t][s]
  size_t base = ((size_t)(b * 16) * 512 + d) * 1024 + tid * 4;

  float res[16][4];
#pragma unroll
  for (int s = 0; s < 16; ++s)
#pragma unroll
    for (int j = 0; j < 4; ++j) res[s][j] = 0.f;

#pragma unroll
  for (int t = 0; t < 16; ++t) {
    f16x4 vp = *(const f16x4*)&VP[base + (size_t)t * 524288];
    float x0 = (float)vp[0], x1 = (float)vp[1], x2 = (float)vp[2], x3 = (float)vp[3];
#pragma unroll
    for (int s = 0; s < 16; ++s) {
      float a = at[t * 16 + s];  // uniform -> scalar load
      res[s][0] += a * x0; res[s][1] += a * x1;
      res[s][2] += a * x2; res[s][3] += a * x3;
    }
  }

#pragma unroll
  for (int s = 0; s < 16; ++s) {
    float4 f = {res[s][0], res[s][1], res[s][2], res[s][3]};
    *(float4*)&out[base + (size_t)s * 524288] = f;
  }
}

// ---------------------------------------------------------------- k_mix (fallback)
// In-place on d_out (fp32 VP), per-thread read set == write set, loads before
// stores -> in-place safe. Used only when workspace can't hold fp16 VP.
__global__ __launch_bounds__(256) void k_mix(float* __restrict__ out,
                                             const float* __restrict__ attnT) {
  int blk = blockIdx.x;
  int b = blk >> 9, d = blk & 511, h = d >> 6;
  int tid = threadIdx.x;
  const float* at = attnT + (b * 8 + h) * 256;  // [t][s]
  size_t base = ((size_t)(b * 16) * 512 + d) * 1024 + tid * 4;

  float res[16][4];
#pragma unroll
  for (int s = 0; s < 16; ++s)
#pragma unroll
    for (int j = 0; j < 4; ++j) res[s][j] = 0.f;

#pragma unroll
  for (int t = 0; t < 16; ++t) {
    float4 vp = *(const float4*)&out[base + (size_t)t * 524288];
#pragma unroll
    for (int s = 0; s < 16; ++s) {
      float a = at[t * 16 + s];
      res[s][0] += a * vp.x; res[s][1] += a * vp.y;
      res[s][2] += a * vp.z; res[s][3] += a * vp.w;
    }
  }

#pragma unroll
  for (int s = 0; s < 16; ++s) {
    float4 f = {res[s][0], res[s][1], res[s][2], res[s][3]};
    *(float4*)&out[base + (size_t)s * 524288] = f;
  }
}

// ---------------------------------------------------------------- launch
extern "C" void kernel_launch(void* const* d_in, const int* in_sizes, int n_in,
                              void* d_out, int out_size, void* d_ws, size_t ws_size,
                              hipStream_t stream) {
  const float* q  = (const float*)d_in[0];
  const float* k  = (const float*)d_in[1];
  const float* v  = (const float*)d_in[2];
  const float* Wq = (const float*)d_in[3];
  const float* Wk = (const float*)d_in[4];
  const float* Wv = (const float*)d_in[5];
  // heads (d_in[6]) is the constant 8 — baked in.

  char* ws = (char*)d_ws;
  unsigned short* vT    = (unsigned short*)ws;                 // 67,108,864 B
  unsigned short* Wv_h  = (unsigned short*)(ws + 67108864);    //    524,288 B
  float* qm    = (float*)(ws + 67633152);                      //    131,072 B
  float* km    = (float*)(ws + 67764224);                      //    131,072 B
  float* attnT = (float*)(ws + 67895296);                      //     32,768 B
  _Float16* VPh = (_Float16*)(ws + 67928064);                  // 67,108,864 B
  float* out   = (float*)d_out;

  const size_t NEED_F16 = 67928064ull + 67108864ull;           // 135,036,928 B
  int use16 = (ws_size >= NEED_F16) ? 1 : 0;

  k_means<<<2048, 256, 0, stream>>>(q, k, qm, km);
  k_trans<<<dim3(16, 8, 16), 256, 0, stream>>>(v, vT);
  k_attn<<<32, 256, 0, stream>>>(qm, km, Wq, Wk, Wv, Wv_h, attnT);
  if (use16) {
    k_gemm<<<dim3(8, 4, 64), 256, 0, stream>>>(Wv_h, vT, (void*)VPh, 1);
    k_mix_f16<<<2048, 256, 0, stream>>>(VPh, out, attnT);
  } else {
    k_gemm<<<dim3(8, 4, 64), 256, 0, stream>>>(Wv_h, vT, (void*)out, 0);
    k_mix<<<2048, 256, 0, stream>>>(out, attnT);
  }
}